// Round 14
// baseline (855.967 us; speedup 1.0000x reference)
//
#include <hip/hip_runtime.h>

constexpr float BN_EPS = 1e-5f;
constexpr int HB = 256;     // histogram blocks (1 per CU, 100KB LDS each)

using short8  = __attribute__((ext_vector_type(8))) short;
using floatx4 = __attribute__((ext_vector_type(4))) float;

__device__ __forceinline__ float bf2f(unsigned short u) {
  return __uint_as_float(((unsigned)u) << 16);
}
__device__ __forceinline__ unsigned short f2bf(float f) {
  union { float f; unsigned u; } v; v.f = f;
  unsigned r = v.u + 0x7FFF + ((v.u >> 16) & 1);   // RNE
  return (unsigned short)(r >> 16);
}

// ---------------- graph preprocessing (LDS histograms, no global atomics) ----------------

__global__ void __launch_bounds__(1024) hist_lds_kernel(const int* __restrict__ keys, int E, int slice,
                                                        unsigned* __restrict__ partials, int NW) {
  extern __shared__ unsigned lds[];
  int tid = threadIdx.x, b = blockIdx.x;
  for (int w = tid; w < NW; w += 1024) lds[w] = 0;
  __syncthreads();
  int e0 = b * slice, e1 = e0 + slice; if (e1 > E) e1 = E;
  for (int e = e0 + tid; e < e1; e += 1024) {
    int n = keys[e];
    atomicAdd(&lds[n >> 2], 1u << (8 * (n & 3)));
  }
  __syncthreads();
  unsigned* out = partials + (size_t)b * NW;
  for (int w = tid; w < NW; w += 1024) out[w] = lds[w];
}

__global__ void combine_kernel(unsigned* __restrict__ pA, const unsigned* __restrict__ pB,
                               float* __restrict__ dis, int* __restrict__ cnt, int NW, int N) {
  int w = blockIdx.x * blockDim.x + threadIdx.x;
  if (w >= NW) return;
  unsigned sumA = 0;
  for (int b = 0; b < HB; ++b) sumA += pA[(size_t)b * NW + w];
  unsigned runB = 0;
  for (int b = 0; b < HB; ++b) {
    unsigned v = pB[(size_t)b * NW + w];
    pA[(size_t)b * NW + w] = runB;               // baseTbl (exclusive prefix)
    runB += v;
  }
  int n0 = w * 4;
#pragma unroll
  for (int j = 0; j < 4; ++j) {
    int n = n0 + j;
    if (n < N) {
      unsigned da = (sumA >> (8 * j)) & 255u;
      unsigned db = (runB >> (8 * j)) & 255u;
      dis[n] = da > 0 ? rsqrtf((float)da) : 0.f;
      cnt[n] = (int)db;
    }
  }
}

__global__ void scan1_kernel(const int* __restrict__ cnt, int N,
                             int* __restrict__ rowptr, int* __restrict__ bsums) {
  int tid = threadIdx.x, lane = tid & 63, wid = tid >> 6;
  int i = blockIdx.x * 256 + tid;
  int v = (i < N) ? cnt[i] : 0;
  int incl = v;
#pragma unroll
  for (int off = 1; off < 64; off <<= 1) {
    int u = __shfl_up(incl, off);
    if (lane >= off) incl += u;
  }
  __shared__ int wt[4];
  if (lane == 63) wt[wid] = incl;
  __syncthreads();
  int woff = 0;
  for (int w = 0; w < wid; ++w) woff += wt[w];
  if (i < N) rowptr[i] = woff + incl - v;
  if (tid == 255) bsums[blockIdx.x] = woff + incl;
}

__global__ void scan2_kernel(int* __restrict__ bsums, int NB, int* __restrict__ rowptr, int N) {
  int tid = threadIdx.x, lane = tid & 63, wid = tid >> 6;
  int v = (tid < NB) ? bsums[tid] : 0;
  int incl = v;
#pragma unroll
  for (int off = 1; off < 64; off <<= 1) {
    int u = __shfl_up(incl, off);
    if (lane >= off) incl += u;
  }
  __shared__ int wt[16];
  if (lane == 63) wt[wid] = incl;
  __syncthreads();
  int woff = 0;
  for (int w = 0; w < wid; ++w) woff += wt[w];
  if (tid < NB) bsums[tid] = woff + incl - v;
  if (tid == blockDim.x - 1) rowptr[N] = woff + incl;
}

__global__ void scan3_kernel(int* __restrict__ rowptr, const int* __restrict__ bsums, int N) {
  int i = blockIdx.x * 256 + threadIdx.x;
  if (i < N) rowptr[i] += bsums[blockIdx.x];
}

// scatter: LDS cursors; writes ONLY the source index (4B) — weights are
// recomputed in the lap kernels from the L2-resident dis[] table.
__global__ void __launch_bounds__(1024) scatter2_kernel(
    const int* __restrict__ src, const int* __restrict__ dst, int E, int slice,
    const unsigned* __restrict__ baseTbl, int NW, const int* __restrict__ rowptr,
    int* __restrict__ srcS) {
  extern __shared__ unsigned lds[];
  int tid = threadIdx.x, b = blockIdx.x;
  const unsigned* base = baseTbl + (size_t)b * NW;
  for (int w = tid; w < NW; w += 1024) lds[w] = base[w];
  __syncthreads();
  int e0 = b * slice, e1 = e0 + slice; if (e1 > E) e1 = E;
  for (int e = e0 + tid; e < e1; e += 1024) {
    int s = src[e], d = dst[e];
    unsigned prev = atomicAdd(&lds[d >> 2], 1u << (8 * (d & 3)));
    int p = rowptr[d] + (int)((prev >> (8 * (d & 3))) & 255u);
    srcS[p] = s;
  }
}

// pack: layer-1 packed buffer [N][16] bf16: cols 0-8 = x|pos|nrm, rest 0
__global__ void pack_kernel(const float* __restrict__ x, const float* __restrict__ pos,
                            const float* __restrict__ nrm, ushort* __restrict__ h0p, int N) {
  int idx = blockIdx.x * blockDim.x + threadIdx.x;
  if (idx < N * 16) {
    int n = idx >> 4, c = idx & 15;
    float v = 0.f;
    if (c < 3) v = x[n * 3 + c];
    else if (c < 6) v = pos[n * 3 + c - 3];
    else if (c < 9) v = nrm[n * 3 + c - 6];
    h0p[idx] = f2bf(v);
  }
}

// ---------------- lap64: bf16 gather -> fp32 accumulate -> bf16 out ----------------
// 1 node per wave; 4 edge-slots x 16 lanes x ushort4. Weight = dis[s] * (-dis[node]).

template <bool AFFINE>
__global__ __launch_bounds__(256) void lap64_kernel(
    const ushort4* __restrict__ vb, ushort4* __restrict__ outb,
    const int* __restrict__ rowptr, const int* __restrict__ srcS,
    const float* __restrict__ dis, const float* __restrict__ st, int N) {
  int tid = threadIdx.x, lane = tid & 63, wid = tid >> 6;
  int node = blockIdx.x * 4 + wid;
  if (node >= N) return;
  int g = lane >> 4, q = lane & 15;
  float disd = -dis[node];
  int r0 = rowptr[node], r1 = rowptr[node + 1];
  float4 a = {0.f, 0.f, 0.f, 0.f}, b = {0.f, 0.f, 0.f, 0.f};
  float ws = 0.f, ws2 = 0.f;
  int k = r0 + g;
  for (; k + 12 < r1; k += 16) {
    int s0 = srcS[k], s1 = srcS[k + 4], s2 = srcS[k + 8], s3 = srcS[k + 12];
    float d0 = dis[s0], d1 = dis[s1], d2 = dis[s2], d3 = dis[s3];
    ushort4 u0 = vb[(size_t)s0 * 16 + q];
    ushort4 u1 = vb[(size_t)s1 * 16 + q];
    ushort4 u2 = vb[(size_t)s2 * 16 + q];
    ushort4 u3 = vb[(size_t)s3 * 16 + q];
    float w0 = d0 * disd, w1 = d1 * disd, w2 = d2 * disd, w3 = d3 * disd;
    ws += w0 + w2; ws2 += w1 + w3;
    a.x = fmaf(w0, bf2f(u0.x), a.x); a.y = fmaf(w0, bf2f(u0.y), a.y);
    a.z = fmaf(w0, bf2f(u0.z), a.z); a.w = fmaf(w0, bf2f(u0.w), a.w);
    b.x = fmaf(w1, bf2f(u1.x), b.x); b.y = fmaf(w1, bf2f(u1.y), b.y);
    b.z = fmaf(w1, bf2f(u1.z), b.z); b.w = fmaf(w1, bf2f(u1.w), b.w);
    a.x = fmaf(w2, bf2f(u2.x), a.x); a.y = fmaf(w2, bf2f(u2.y), a.y);
    a.z = fmaf(w2, bf2f(u2.z), a.z); a.w = fmaf(w2, bf2f(u2.w), a.w);
    b.x = fmaf(w3, bf2f(u3.x), b.x); b.y = fmaf(w3, bf2f(u3.y), b.y);
    b.z = fmaf(w3, bf2f(u3.z), b.z); b.w = fmaf(w3, bf2f(u3.w), b.w);
  }
  for (; k < r1; k += 4) {
    int s0 = srcS[k];
    float w0 = dis[s0] * disd;
    ushort4 u0 = vb[(size_t)s0 * 16 + q];
    ws += w0;
    a.x = fmaf(w0, bf2f(u0.x), a.x); a.y = fmaf(w0, bf2f(u0.y), a.y);
    a.z = fmaf(w0, bf2f(u0.z), a.z); a.w = fmaf(w0, bf2f(u0.w), a.w);
  }
  a.x += b.x; a.y += b.y; a.z += b.z; a.w += b.w; ws += ws2;
  a.x += __shfl_xor(a.x, 16); a.y += __shfl_xor(a.y, 16);
  a.z += __shfl_xor(a.z, 16); a.w += __shfl_xor(a.w, 16);
  ws += __shfl_xor(ws, 16);
  a.x += __shfl_xor(a.x, 32); a.y += __shfl_xor(a.y, 32);
  a.z += __shfl_xor(a.z, 32); a.w += __shfl_xor(a.w, 32);
  ws += __shfl_xor(ws, 32);
  if (g == 0) {
    float4 o = a;
    if (AFFINE) {
      float4 s4 = *(const float4*)(st + q * 4);
      float4 t4 = *(const float4*)(st + 64 + q * 4);
      o.x = fmaf(a.x, s4.x, ws * t4.x);
      o.y = fmaf(a.y, s4.y, ws * t4.y);
      o.z = fmaf(a.z, s4.z, ws * t4.z);
      o.w = fmaf(a.w, s4.w, ws * t4.w);
    }
    ushort4 ub;
    ub.x = f2bf(o.x); ub.y = f2bf(o.y); ub.z = f2bf(o.z); ub.w = f2bf(o.w);
    outb[(size_t)node * 16 + q] = ub;
  }
}

// lap16: packed [N][16] bf16 gather (3.2MB working set -> L2 resident).
// 4 nodes/wave; per node: 4 edge-groups x 4 lanes (q = ushort4 within 32B row).

__global__ __launch_bounds__(256) void lap16_kernel(const ushort4* __restrict__ vb,
                                                    ushort4* __restrict__ outb,
                                                    const int* __restrict__ rowptr,
                                                    const int* __restrict__ srcS,
                                                    const float* __restrict__ dis, int N) {
  int tid = threadIdx.x, lane = tid & 63, wid = tid >> 6;
  int node = (blockIdx.x * 4 + wid) * 4 + (lane >> 4);
  int sub = lane & 15, g = sub >> 2, q = sub & 3;
  float4 acc = {0.f, 0.f, 0.f, 0.f};
  if (node < N) {
    float disd = -dis[node];
    int r0 = rowptr[node], r1 = rowptr[node + 1];
    int k = r0 + g;
    for (; k + 4 < r1; k += 8) {
      int sa = srcS[k], sb = srcS[k + 4];
      float wa = dis[sa] * disd, wb = dis[sb] * disd;
      ushort4 ua = vb[(size_t)sa * 4 + q];
      ushort4 ub2 = vb[(size_t)sb * 4 + q];
      acc.x = fmaf(wa, bf2f(ua.x), acc.x); acc.y = fmaf(wa, bf2f(ua.y), acc.y);
      acc.z = fmaf(wa, bf2f(ua.z), acc.z); acc.w = fmaf(wa, bf2f(ua.w), acc.w);
      acc.x = fmaf(wb, bf2f(ub2.x), acc.x); acc.y = fmaf(wb, bf2f(ub2.y), acc.y);
      acc.z = fmaf(wb, bf2f(ub2.z), acc.z); acc.w = fmaf(wb, bf2f(ub2.w), acc.w);
    }
    if (k < r1) {
      int s = srcS[k];
      float w = dis[s] * disd;
      ushort4 u = vb[(size_t)s * 4 + q];
      acc.x = fmaf(w, bf2f(u.x), acc.x); acc.y = fmaf(w, bf2f(u.y), acc.y);
      acc.z = fmaf(w, bf2f(u.z), acc.z); acc.w = fmaf(w, bf2f(u.w), acc.w);
    }
  }
  acc.x += __shfl_xor(acc.x, 4); acc.y += __shfl_xor(acc.y, 4);
  acc.z += __shfl_xor(acc.z, 4); acc.w += __shfl_xor(acc.w, 4);
  acc.x += __shfl_xor(acc.x, 8); acc.y += __shfl_xor(acc.y, 8);
  acc.z += __shfl_xor(acc.z, 8); acc.w += __shfl_xor(acc.w, 8);
  if (node < N && g == 0) {
    ushort4 ub;
    ub.x = f2bf(acc.x); ub.y = f2bf(acc.y); ub.z = f2bf(acc.z); ub.w = f2bf(acc.w);
    outb[(size_t)node * 4 + q] = ub;
  }
}

// ---------------- W' builder (fragment-ordered bf16 + folded bias) ----------------

template <int NMAT, int F_OUT, bool NORMH>
__device__ __forceinline__ void buildW(const float* __restrict__ W, const float* __restrict__ bias,
                                       const float* stPrev,
                                       ushort* __restrict__ fragW, float* __restrict__ biasP,
                                       int f_in_real, int tid, int nth) {
  constexpr int NFRAG = F_OUT / 16;
  constexpr int NKF = NMAT * 2;
  constexpr int TOTF = NKF * NFRAG;
  const int S = f_in_real * F_OUT;
  for (int idx = tid; idx < TOTF * 512; idx += nth) {
    int f = idx >> 9;
    int r = idx & 511;
    int l = r >> 3, j = r & 7;
    int kf = f / NFRAG, nc = f - kf * NFRAG;
    int c = nc * 16 + (l & 15);
    float v = 0.f;
    if (NMAT == 3) {
      int k = (kf & 1) * 32 + (l >> 4) * 8 + j;
      int m = kf >> 1;
      int b = k * F_OUT + c;
      if (m == 0)      { v = W[b] - W[2 * S + b]; if (NORMH) v *= stPrev[k]; }
      else if (m == 1)   v = W[S + b];
      else               v = 2.f * W[2 * S + b];
    } else {
      int kg = kf * 32 + (l >> 4) * 8 + j;   // global k 0..63
      int sub = kg >> 4, kk = kg & 15;
      if (sub < 3 && kk < f_in_real) {
        int b = kk * F_OUT + c;
        if (sub == 0)      v = W[b] - W[2 * S + b];
        else if (sub == 1) v = W[S + b];
        else               v = 2.f * W[2 * S + b];
      }
    }
    fragW[idx] = f2bf(v);
  }
  if (tid < F_OUT) {
    float acc = bias[tid];
    if (NORMH) {
      for (int k = 0; k < 64; ++k)
        acc += stPrev[64 + k] * (W[k * F_OUT + tid] - W[2 * S + k * F_OUT + tid]);
    }
    biasP[tid] = acc;
  }
}

__global__ void __launch_bounds__(1024) wprep1_kernel(const float* __restrict__ W,
                                                      const float* __restrict__ bias,
                                                      ushort* __restrict__ fragW,
                                                      float* __restrict__ biasP, int finr) {
  buildW<1, 64, false>(W, bias, nullptr, fragW, biasP, finr, threadIdx.x, 1024);
}

// ---------------- MFMA mm ----------------
// NMAT=3: A0/A1/A2 = [N][64] bf16 buffers. NMAT=1: A0/A1/A2 = packed [N][16]
// buffers (h16p,t1p,t2p); k>=48 reads a 64B zero stub (Az).
// mfma_f32_16x16x32_bf16: A: lane l -> A[l&15][(l>>4)*8+j];
// B: lane l -> B[(l>>4)*8+j][l&15]; D: lane l, reg r -> C[(l>>4)*4+r][l&15].

template <int NMAT, int F_OUT>
__global__ __launch_bounds__(256) void mmfma_kernel(
    const ushort* __restrict__ A0, const ushort* __restrict__ A1, const ushort* __restrict__ A2,
    const ushort* __restrict__ Az,
    ushort* __restrict__ outb,
    const ushort* __restrict__ fragW, const float* __restrict__ biasP,
    const float* __restrict__ aP,
    float* __restrict__ bp, int N, int ntiles) {
  constexpr int NFRAG = F_OUT / 16;
  constexpr int NKF = NMAT * 2;
  constexpr int TOTF = NKF * NFRAG;
  __shared__ float red[4 * 2 * 64];          // [wave][stat][col]
  int tid = threadIdx.x;
  for (int idx = tid; idx < 512; idx += 256) red[idx] = 0.f;
  __syncthreads();

  const int lane = tid & 63, wid = tid >> 6;
  const int rg = lane >> 4, cl = lane & 15;
  const float alpha = aP[0];

  short8 bfr[TOTF];
#pragma unroll
  for (int f = 0; f < TOTF; ++f)
    bfr[f] = *(const short8*)&fragW[f * 512 + lane * 8];
  float bi[NFRAG];
#pragma unroll
  for (int nc = 0; nc < NFRAG; ++nc) bi[nc] = biasP[nc * 16 + cl];

  float ssum[NFRAG], ssq[NFRAG];
#pragma unroll
  for (int nc = 0; nc < NFRAG; ++nc) { ssum[nc] = 0.f; ssq[nc] = 0.f; }

  for (int tile = blockIdx.x; tile < ntiles; tile += gridDim.x) {
    const int nb = tile * 64 + wid * 16;
    floatx4 acc[NFRAG];
#pragma unroll
    for (int nc = 0; nc < NFRAG; ++nc) acc[nc] = (floatx4){0.f, 0.f, 0.f, 0.f};

#pragma unroll
    for (int kf = 0; kf < NKF; ++kf) {
      short8 a;
      if (NMAT == 3) {
        const ushort* Ap = (kf < 2 ? A0 : (kf < 4 ? A1 : A2));
        a = *(const short8*)(Ap + (size_t)(nb + cl) * 64 + (kf & 1) * 32 + rg * 8);
      } else {
        int k0 = kf * 32 + rg * 8;           // 0..56
        int sb = k0 >> 4;                    // 0..3 (per-lane)
        const ushort* Ap = sb == 0 ? A0 : (sb == 1 ? A1 : (sb == 2 ? A2 : Az));
        size_t off = (sb == 3) ? 0 : ((size_t)(nb + cl) * 16 + (k0 & 15));
        a = *(const short8*)(Ap + off);
      }
#pragma unroll
      for (int nc = 0; nc < NFRAG; ++nc)
        acc[nc] = __builtin_amdgcn_mfma_f32_16x16x32_bf16(a, bfr[kf * NFRAG + nc], acc[nc], 0, 0, 0);
    }

#pragma unroll
    for (int nc = 0; nc < NFRAG; ++nc) {
      int c = nc * 16 + cl;
#pragma unroll
      for (int r = 0; r < 4; ++r) {
        int node = nb + rg * 4 + r;
        if (node < N) {
          float t = acc[nc][r] + bi[nc];
          t = t > 0.f ? t : alpha * t;
          ssum[nc] += t; ssq[nc] += t * t;
          outb[(size_t)node * 64 + c] = f2bf(t);
        }
      }
    }
  }

#pragma unroll
  for (int nc = 0; nc < NFRAG; ++nc) {
    ssum[nc] += __shfl_xor(ssum[nc], 16); ssum[nc] += __shfl_xor(ssum[nc], 32);
    ssq[nc]  += __shfl_xor(ssq[nc], 16);  ssq[nc]  += __shfl_xor(ssq[nc], 32);
  }
  if (lane < 16) {
#pragma unroll
    for (int nc = 0; nc < NFRAG; ++nc) {
      red[(wid * 2 + 0) * 64 + nc * 16 + lane] = ssum[nc];
      red[(wid * 2 + 1) * 64 + nc * 16 + lane] = ssq[nc];
    }
  }
  __syncthreads();
  if (tid < 128) {
    int col = tid & 63, stat = tid >> 6;
    float tot = red[(0 * 2 + stat) * 64 + col] + red[(1 * 2 + stat) * 64 + col]
              + red[(2 * 2 + stat) * 64 + col] + red[(3 * 2 + stat) * 64 + col];
    bp[(size_t)blockIdx.x * 128 + stat * 64 + col] = tot;
  }
}

// ---------------- BN stats reduce -> affine (s,t); optionally builds next layer's W' ----------------

template <int NMAT_N, int F_OUT_N, bool BUILD>
__global__ void stats_kernel(const float* __restrict__ bp, int nb,
                             const float* __restrict__ g, const float* __restrict__ be,
                             float* __restrict__ st, int F_OUT, float invN,
                             const float* __restrict__ Wn, const float* __restrict__ bn,
                             ushort* __restrict__ fragWn, float* __restrict__ biasPn, int finrN) {
  __shared__ float red[1024];
  __shared__ float stSh[128];
  int tid = threadIdx.x;
  int t = tid & 127, c = tid >> 7;
  float s = 0.f;
  for (int w = c; w < nb; w += 8) s += bp[(size_t)w * 128 + t];
  red[tid] = s;
  __syncthreads();
  if (tid < 128) {
    float tot = 0.f;
    for (int cc = 0; cc < 8; ++cc) tot += red[cc * 128 + tid];
    red[tid] = tot;
  }
  __syncthreads();
  if (tid < F_OUT) {
    float sum = red[tid], sq = red[64 + tid];
    float mu = sum * invN;
    float var = sq * invN - mu * mu;
    float sc = g[tid] * rsqrtf(var + BN_EPS);
    st[tid] = sc;        stSh[tid] = sc;
    st[64 + tid] = be[tid] - mu * sc;
    stSh[64 + tid] = be[tid] - mu * sc;
  }
  if (BUILD) {
    __syncthreads();
    buildW<NMAT_N, F_OUT_N, true>(Wn, bn, stSh, fragWn, biasPn, finrN, tid, 1024);
  }
}

// ---------------- final MLP: register-tiled GEMM chain ----------------

__global__ __launch_bounds__(256) void mlp_kernel(const ushort* __restrict__ hb,
    const float* __restrict__ st,
    const float* __restrict__ w1, const float* __restrict__ b1,
    const float* __restrict__ w2, const float* __restrict__ b2,
    const float* __restrict__ w3, const float* __restrict__ b3,
    float* __restrict__ out, int N, int ntiles) {
  __shared__ float Wl[3][1024];
  __shared__ float Bl[3][32];
  __shared__ float S4[32], T4[32];
  __shared__ float act[2][128][36];
  int tid = threadIdx.x;
  for (int idx = tid; idx < 1024; idx += 256) {
    Wl[0][idx] = w1[idx];
    Wl[1][idx] = w2[idx];
    Wl[2][idx] = w3[idx];
  }
  if (tid < 32) {
    Bl[0][tid] = b1[tid]; Bl[1][tid] = b2[tid]; Bl[2][tid] = b3[tid];
    S4[tid] = st[tid]; T4[tid] = st[64 + tid];
  }
  __syncthreads();

  const int cg = tid & 7, ng = tid >> 3;
  const int c0 = cg * 4;
  const int nl = ng * 4;

  for (int tile = blockIdx.x; tile < ntiles; tile += gridDim.x) {
    const int node0 = tile * 128 + nl;
    float acc[4][4];

#pragma unroll
    for (int j = 0; j < 4; ++j)
#pragma unroll
      for (int c = 0; c < 4; ++c) acc[j][c] = 0.f;
#pragma unroll
    for (int kb = 0; kb < 8; ++kb) {
      float ar[4][4];
#pragma unroll
      for (int j = 0; j < 4; ++j) {
        int node = node0 + j;
        if (node < N) {
          ushort4 u = *(const ushort4*)(hb + (size_t)node * 64 + kb * 4);
          ar[j][0] = fmaf(bf2f(u.x), S4[kb * 4 + 0], T4[kb * 4 + 0]);
          ar[j][1] = fmaf(bf2f(u.y), S4[kb * 4 + 1], T4[kb * 4 + 1]);
          ar[j][2] = fmaf(bf2f(u.z), S4[kb * 4 + 2], T4[kb * 4 + 2]);
          ar[j][3] = fmaf(bf2f(u.w), S4[kb * 4 + 3], T4[kb * 4 + 3]);
        } else {
          ar[j][0] = ar[j][1] = ar[j][2] = ar[j][3] = 0.f;
        }
      }
#pragma unroll
      for (int kk = 0; kk < 4; ++kk) {
        float br[4];
        *(float4*)br = *(const float4*)(&Wl[0][(kb * 4 + kk) * 32 + c0]);
#pragma unroll
        for (int j = 0; j < 4; ++j)
#pragma unroll
          for (int c = 0; c < 4; ++c)
            acc[j][c] = fmaf(ar[j][kk], br[c], acc[j][c]);
      }
    }
#pragma unroll
    for (int j = 0; j < 4; ++j) {
      float v[4];
#pragma unroll
      for (int c = 0; c < 4; ++c) v[c] = fmaxf(acc[j][c] + Bl[0][c0 + c], 0.f);
      *(float4*)(&act[0][nl + j][c0]) = *(float4*)v;
    }
    __syncthreads();

#pragma unroll
    for (int j = 0; j < 4; ++j)
#pragma unroll
      for (int c = 0; c < 4; ++c) acc[j][c] = 0.f;
#pragma unroll
    for (int kb = 0; kb < 8; ++kb) {
      float ar[4][4];
#pragma unroll
      for (int j = 0; j < 4; ++j)
        *(float4*)ar[j] = *(const float4*)(&act[0][nl + j][kb * 4]);
#pragma unroll
      for (int kk = 0; kk < 4; ++kk) {
        float br[4];
        *(float4*)br = *(const float4*)(&Wl[1][(kb * 4 + kk) * 32 + c0]);
#pragma unroll
        for (int j = 0; j < 4; ++j)
#pragma unroll
          for (int c = 0; c < 4; ++c)
            acc[j][c] = fmaf(ar[j][kk], br[c], acc[j][c]);
      }
    }
#pragma unroll
    for (int j = 0; j < 4; ++j) {
      float v[4];
#pragma unroll
      for (int c = 0; c < 4; ++c) v[c] = fmaxf(acc[j][c] + Bl[1][c0 + c], 0.f);
      *(float4*)(&act[1][nl + j][c0]) = *(float4*)v;
    }
    __syncthreads();

#pragma unroll
    for (int j = 0; j < 4; ++j)
#pragma unroll
      for (int c = 0; c < 4; ++c) acc[j][c] = 0.f;
#pragma unroll
    for (int kb = 0; kb < 8; ++kb) {
      float ar[4][4];
#pragma unroll
      for (int j = 0; j < 4; ++j)
        *(float4*)ar[j] = *(const float4*)(&act[1][nl + j][kb * 4]);
#pragma unroll
      for (int kk = 0; kk < 4; ++kk) {
        float br[4];
        *(float4*)br = *(const float4*)(&Wl[2][(kb * 4 + kk) * 32 + c0]);
#pragma unroll
        for (int j = 0; j < 4; ++j)
#pragma unroll
          for (int c = 0; c < 4; ++c)
            acc[j][c] = fmaf(ar[j][kk], br[c], acc[j][c]);
      }
    }
#pragma unroll
    for (int j = 0; j < 4; ++j) {
      int node = node0 + j;
      if (node < N) {
        float v[4];
#pragma unroll
        for (int c = 0; c < 4; ++c) v[c] = acc[j][c] + Bl[2][c0 + c];
        *(float4*)(out + (size_t)node * 32 + c0) = *(float4*)v;
      }
    }
    __syncthreads();
  }
}

// ---------------- host ----------------

extern "C" void kernel_launch(void* const* d_in, const int* in_sizes, int n_in,
                              void* d_out, int out_size, void* d_ws, size_t ws_size,
                              hipStream_t stream) {
  const float* x   = (const float*)d_in[0];
  const float* pos = (const float*)d_in[1];
  const float* nrm = (const float*)d_in[2];
  const int*   ei  = (const int*)d_in[3];
  const float* W1p = (const float*)d_in[4];
  const float* b1p = (const float*)d_in[5];
  const float* a1p = (const float*)d_in[6];
  const float* g1p = (const float*)d_in[7];
  const float* be1p= (const float*)d_in[8];
  const float* W2p = (const float*)d_in[9];
  const float* b2p = (const float*)d_in[10];
  const float* a2p = (const float*)d_in[11];
  const float* g2p = (const float*)d_in[12];
  const float* be2p= (const float*)d_in[13];
  const float* W3p = (const float*)d_in[14];
  const float* b3p = (const float*)d_in[15];
  const float* a3p = (const float*)d_in[16];
  const float* g3p = (const float*)d_in[17];
  const float* be3p= (const float*)d_in[18];
  const float* W4p = (const float*)d_in[19];
  const float* b4p = (const float*)d_in[20];
  const float* a4p = (const float*)d_in[21];
  const float* g4p = (const float*)d_in[22];
  const float* be4p= (const float*)d_in[23];
  const float* h1w = (const float*)d_in[24];
  const float* h1b = (const float*)d_in[25];
  const float* h2w = (const float*)d_in[26];
  const float* h2b = (const float*)d_in[27];
  const float* h3w = (const float*)d_in[28];
  const float* h3b = (const float*)d_in[29];

  const int N = in_sizes[0] / 3;
  const int E = in_sizes[3] / 2;
  const int* src = ei;
  const int* dst = ei + E;

  const int NW = (N + 3) / 4;
  const size_t ldsBytes = (size_t)NW * 4;
  const int slice = (E + HB - 1) / HB;

  char* p = (char*)d_ws;
  auto alloc = [&](size_t bytes) -> void* {
    void* r = (void*)p;
    p += (bytes + 255) & ~(size_t)255;
    return r;
  };
  float*    dis      = (float*)   alloc((size_t)N * 4);
  int*      rowptr   = (int*)     alloc((size_t)(N + 1) * 4);
  int*      cnt      = (int*)     alloc((size_t)N * 4);
  int*      bsums    = (int*)     alloc(4096 * 4);
  unsigned* partialsA= (unsigned*)alloc((size_t)HB * NW * 4);   // -> baseTbl
  unsigned* partialsB= (unsigned*)alloc((size_t)HB * NW * 4);   // -> srcS
  int*      srcS     = (int*)partialsB;
  ushort*   bufHb    = (ushort*)  alloc((size_t)N * 64 * 2);
  ushort*   bufT1b   = (ushort*)  alloc((size_t)N * 64 * 2);
  ushort*   bufT2b   = (ushort*)  alloc((size_t)N * 64 * 2);
  ushort*   h16p     = (ushort*)  alloc((size_t)N * 16 * 2);    // packed layer-1
  ushort*   t1p      = (ushort*)  alloc((size_t)N * 16 * 2);
  ushort*   t2p      = (ushort*)  alloc((size_t)N * 16 * 2);
  ushort*   zerob    = (ushort*)  alloc(64);
  const int MMB = 782;
  float*    bp       = (float*)   alloc((size_t)MMB * 128 * 4);
  float*    stats    = (float*)   alloc(512 * 4);
  ushort*   fragW    = (ushort*)  alloc(24 * 512 * 2);          // max TOTF=24
  float*    biasP    = (float*)   alloc(64 * 4);
  float* st1 = stats, *st2 = stats + 128, *st3 = stats + 256, *st4 = stats + 384;

  int gN = (N + 255) / 256;
  hipMemsetAsync(zerob, 0, 64, stream);
  hist_lds_kernel<<<HB, 1024, ldsBytes, stream>>>(src, E, slice, partialsA, NW);
  hist_lds_kernel<<<HB, 1024, ldsBytes, stream>>>(dst, E, slice, partialsB, NW);
  combine_kernel<<<(NW + 255) / 256, 256, 0, stream>>>(partialsA, partialsB, dis, cnt, NW, N);
  scan1_kernel<<<gN, 256, 0, stream>>>(cnt, N, rowptr, bsums);
  scan2_kernel<<<1, 1024, 0, stream>>>(bsums, gN, rowptr, N);
  scan3_kernel<<<gN, 256, 0, stream>>>(rowptr, bsums, N);
  scatter2_kernel<<<HB, 1024, ldsBytes, stream>>>(src, dst, E, slice, partialsA, NW, rowptr, srcS);
  pack_kernel<<<(N * 16 + 255) / 256, 256, 0, stream>>>(x, pos, nrm, h16p, N);
  wprep1_kernel<<<1, 1024, 0, stream>>>(W1p, b1p, fragW, biasP, 9);

  const float invN = 1.f / (float)N;
  int g64 = (N + 3) / 4, g16 = (N + 15) / 16;
  const int ntiles = (N + 63) / 64;
  const int ntilesM = (N + 127) / 128;

  // layer 1: packed h16p -> t1p -> t2p; mmfma reads 3 packed buffers + zero
  lap16_kernel<<<g16, 256, 0, stream>>>((const ushort4*)h16p, (ushort4*)t1p, rowptr, srcS, dis, N);
  lap16_kernel<<<g16, 256, 0, stream>>>((const ushort4*)t1p, (ushort4*)t2p, rowptr, srcS, dis, N);
  mmfma_kernel<1, 64><<<MMB, 256, 0, stream>>>(h16p, t1p, t2p, zerob, bufHb,
      fragW, biasP, a1p, bp, N, ntiles);
  stats_kernel<3, 64, true><<<1, 1024, 0, stream>>>(bp, MMB, g1p, be1p, st1, 64, invN,
      W2p, b2p, fragW, biasP, 64);

  // layer 2 (in-place on bufHb)
  lap64_kernel<true><<<g64, 256, 0, stream>>>((const ushort4*)bufHb, (ushort4*)bufT1b,
      rowptr, srcS, dis, st1, N);
  lap64_kernel<false><<<g64, 256, 0, stream>>>((const ushort4*)bufT1b, (ushort4*)bufT2b,
      rowptr, srcS, dis, nullptr, N);
  mmfma_kernel<3, 64><<<MMB, 256, 0, stream>>>(bufHb, bufT1b, bufT2b, nullptr, bufHb,
      fragW, biasP, a2p, bp, N, ntiles);
  stats_kernel<3, 64, true><<<1, 1024, 0, stream>>>(bp, MMB, g2p, be2p, st2, 64, invN,
      W3p, b3p, fragW, biasP, 64);

  // layer 3
  lap64_kernel<true><<<g64, 256, 0, stream>>>((const ushort4*)bufHb, (ushort4*)bufT1b,
      rowptr, srcS, dis, st2, N);
  lap64_kernel<false><<<g64, 256, 0, stream>>>((const ushort4*)bufT1b, (ushort4*)bufT2b,
      rowptr, srcS, dis, nullptr, N);
  mmfma_kernel<3, 64><<<MMB, 256, 0, stream>>>(bufHb, bufT1b, bufT2b, nullptr, bufHb,
      fragW, biasP, a3p, bp, N, ntiles);
  stats_kernel<3, 32, true><<<1, 1024, 0, stream>>>(bp, MMB, g3p, be3p, st3, 64, invN,
      W4p, b4p, fragW, biasP, 64);

  // layer 4: 64 -> 32 (rows stride 64, cols 0-31 rewritten)
  lap64_kernel<true><<<g64, 256, 0, stream>>>((const ushort4*)bufHb, (ushort4*)bufT1b,
      rowptr, srcS, dis, st3, N);
  lap64_kernel<false><<<g64, 256, 0, stream>>>((const ushort4*)bufT1b, (ushort4*)bufT2b,
      rowptr, srcS, dis, nullptr, N);
  mmfma_kernel<3, 32><<<MMB, 256, 0, stream>>>(bufHb, bufT1b, bufT2b, nullptr, bufHb,
      fragW, biasP, a4p, bp, N, ntiles);
  stats_kernel<3, 64, false><<<1, 1024, 0, stream>>>(bp, MMB, g4p, be4p, st4, 32, invN,
      nullptr, nullptr, nullptr, nullptr, 0);

  // final MLP (applies st4 affine on load)
  mlp_kernel<<<ntilesM, 256, 0, stream>>>(bufHb, st4, h1w, h1b, h2w, h2b, h3w, h3b,
      (float*)d_out, N, ntilesM);
}

// Round 15
// 801.827 us; speedup vs baseline: 1.0675x; 1.0675x over previous
//
#include <hip/hip_runtime.h>

constexpr float BN_EPS = 1e-5f;
constexpr int HB = 256;     // histogram blocks (1 per CU, 100KB LDS each)

using short8  = __attribute__((ext_vector_type(8))) short;
using floatx4 = __attribute__((ext_vector_type(4))) float;

__device__ __forceinline__ float bf2f(unsigned short u) {
  return __uint_as_float(((unsigned)u) << 16);
}
__device__ __forceinline__ unsigned short f2bf(float f) {
  union { float f; unsigned u; } v; v.f = f;
  unsigned r = v.u + 0x7FFF + ((v.u >> 16) & 1);   // RNE
  return (unsigned short)(r >> 16);
}

// ---------------- graph preprocessing (LDS histograms, no global atomics) ----------------

__global__ void __launch_bounds__(1024) hist_lds_kernel(const int* __restrict__ keys, int E, int slice,
                                                        unsigned* __restrict__ partials, int NW) {
  extern __shared__ unsigned lds[];
  int tid = threadIdx.x, b = blockIdx.x;
  for (int w = tid; w < NW; w += 1024) lds[w] = 0;
  __syncthreads();
  int e0 = b * slice, e1 = e0 + slice; if (e1 > E) e1 = E;
  for (int e = e0 + tid; e < e1; e += 1024) {
    int n = keys[e];
    atomicAdd(&lds[n >> 2], 1u << (8 * (n & 3)));
  }
  __syncthreads();
  unsigned* out = partials + (size_t)b * NW;
  for (int w = tid; w < NW; w += 1024) out[w] = lds[w];
}

__global__ void combine_kernel(unsigned* __restrict__ pA, const unsigned* __restrict__ pB,
                               float* __restrict__ dis, int* __restrict__ cnt, int NW, int N) {
  int w = blockIdx.x * blockDim.x + threadIdx.x;
  if (w >= NW) return;
  unsigned sumA = 0;
  for (int b = 0; b < HB; ++b) sumA += pA[(size_t)b * NW + w];
  unsigned runB = 0;
  for (int b = 0; b < HB; ++b) {
    unsigned v = pB[(size_t)b * NW + w];
    pA[(size_t)b * NW + w] = runB;               // baseTbl (exclusive prefix)
    runB += v;
  }
  int n0 = w * 4;
#pragma unroll
  for (int j = 0; j < 4; ++j) {
    int n = n0 + j;
    if (n < N) {
      unsigned da = (sumA >> (8 * j)) & 255u;
      unsigned db = (runB >> (8 * j)) & 255u;
      dis[n] = da > 0 ? rsqrtf((float)da) : 0.f;
      cnt[n] = (int)db;
    }
  }
}

__global__ void scan1_kernel(const int* __restrict__ cnt, int N,
                             int* __restrict__ rowptr, int* __restrict__ bsums) {
  int tid = threadIdx.x, lane = tid & 63, wid = tid >> 6;
  int i = blockIdx.x * 256 + tid;
  int v = (i < N) ? cnt[i] : 0;
  int incl = v;
#pragma unroll
  for (int off = 1; off < 64; off <<= 1) {
    int u = __shfl_up(incl, off);
    if (lane >= off) incl += u;
  }
  __shared__ int wt[4];
  if (lane == 63) wt[wid] = incl;
  __syncthreads();
  int woff = 0;
  for (int w = 0; w < wid; ++w) woff += wt[w];
  if (i < N) rowptr[i] = woff + incl - v;
  if (tid == 255) bsums[blockIdx.x] = woff + incl;
}

__global__ void scan2_kernel(int* __restrict__ bsums, int NB, int* __restrict__ rowptr, int N) {
  int tid = threadIdx.x, lane = tid & 63, wid = tid >> 6;
  int v = (tid < NB) ? bsums[tid] : 0;
  int incl = v;
#pragma unroll
  for (int off = 1; off < 64; off <<= 1) {
    int u = __shfl_up(incl, off);
    if (lane >= off) incl += u;
  }
  __shared__ int wt[16];
  if (lane == 63) wt[wid] = incl;
  __syncthreads();
  int woff = 0;
  for (int w = 0; w < wid; ++w) woff += wt[w];
  if (tid < NB) bsums[tid] = woff + incl - v;
  if (tid == blockDim.x - 1) rowptr[N] = woff + incl;
}

__global__ void scan3_kernel(int* __restrict__ rowptr, const int* __restrict__ bsums, int N) {
  int i = blockIdx.x * 256 + threadIdx.x;
  if (i < N) rowptr[i] += bsums[blockIdx.x];
}

// scatter: LDS cursors; writes (src, weight) int2 — one 8B load serves the laps.
__global__ void __launch_bounds__(1024) scatter2_kernel(
    const int* __restrict__ src, const int* __restrict__ dst, int E, int slice,
    const unsigned* __restrict__ baseTbl, int NW, const int* __restrict__ rowptr,
    const float* __restrict__ dis, int2* __restrict__ pk) {
  extern __shared__ unsigned lds[];
  int tid = threadIdx.x, b = blockIdx.x;
  const unsigned* base = baseTbl + (size_t)b * NW;
  for (int w = tid; w < NW; w += 1024) lds[w] = base[w];
  __syncthreads();
  int e0 = b * slice, e1 = e0 + slice; if (e1 > E) e1 = E;
  for (int e = e0 + tid; e < e1; e += 1024) {
    int s = src[e], d = dst[e];
    unsigned prev = atomicAdd(&lds[d >> 2], 1u << (8 * (d & 3)));
    int p = rowptr[d] + (int)((prev >> (8 * (d & 3))) & 255u);
    pk[p] = make_int2(s, __float_as_int(-dis[s] * dis[d]));
  }
}

// pack: layer-1 packed buffer [N][16] bf16: cols 0-8 = x|pos|nrm, rest 0
__global__ void pack_kernel(const float* __restrict__ x, const float* __restrict__ pos,
                            const float* __restrict__ nrm, ushort* __restrict__ h0p, int N) {
  int idx = blockIdx.x * blockDim.x + threadIdx.x;
  if (idx < N * 16) {
    int n = idx >> 4, c = idx & 15;
    float v = 0.f;
    if (c < 3) v = x[n * 3 + c];
    else if (c < 6) v = pos[n * 3 + c - 3];
    else if (c < 9) v = nrm[n * 3 + c - 6];
    h0p[idx] = f2bf(v);
  }
}

// ---------------- lap64: bf16 gather -> fp32 accumulate -> bf16 out ----------------
// 1 node per wave; 4 edge-slots x 16 lanes x ushort4 (R13-proven: 24 VGPR, 74us).

template <bool AFFINE>
__global__ __launch_bounds__(256) void lap64_kernel(
    const ushort4* __restrict__ vb, ushort4* __restrict__ outb,
    const int* __restrict__ rowptr, const int2* __restrict__ pk,
    const float* __restrict__ st, int N) {
  int tid = threadIdx.x, lane = tid & 63, wid = tid >> 6;
  int node = blockIdx.x * 4 + wid;
  if (node >= N) return;
  int g = lane >> 4, q = lane & 15;
  int r0 = rowptr[node], r1 = rowptr[node + 1];
  float4 a = {0.f, 0.f, 0.f, 0.f}, b = {0.f, 0.f, 0.f, 0.f};
  float ws = 0.f, ws2 = 0.f;
  int k = r0 + g;
  for (; k + 12 < r1; k += 16) {
    int2 p0 = pk[k], p1 = pk[k + 4], p2 = pk[k + 8], p3 = pk[k + 12];
    ushort4 u0 = vb[(size_t)p0.x * 16 + q];
    ushort4 u1 = vb[(size_t)p1.x * 16 + q];
    ushort4 u2 = vb[(size_t)p2.x * 16 + q];
    ushort4 u3 = vb[(size_t)p3.x * 16 + q];
    float w0 = __int_as_float(p0.y), w1 = __int_as_float(p1.y);
    float w2 = __int_as_float(p2.y), w3 = __int_as_float(p3.y);
    ws += w0 + w2; ws2 += w1 + w3;
    a.x = fmaf(w0, bf2f(u0.x), a.x); a.y = fmaf(w0, bf2f(u0.y), a.y);
    a.z = fmaf(w0, bf2f(u0.z), a.z); a.w = fmaf(w0, bf2f(u0.w), a.w);
    b.x = fmaf(w1, bf2f(u1.x), b.x); b.y = fmaf(w1, bf2f(u1.y), b.y);
    b.z = fmaf(w1, bf2f(u1.z), b.z); b.w = fmaf(w1, bf2f(u1.w), b.w);
    a.x = fmaf(w2, bf2f(u2.x), a.x); a.y = fmaf(w2, bf2f(u2.y), a.y);
    a.z = fmaf(w2, bf2f(u2.z), a.z); a.w = fmaf(w2, bf2f(u2.w), a.w);
    b.x = fmaf(w3, bf2f(u3.x), b.x); b.y = fmaf(w3, bf2f(u3.y), b.y);
    b.z = fmaf(w3, bf2f(u3.z), b.z); b.w = fmaf(w3, bf2f(u3.w), b.w);
  }
  for (; k < r1; k += 4) {
    int2 p0 = pk[k];
    ushort4 u0 = vb[(size_t)p0.x * 16 + q];
    float w0 = __int_as_float(p0.y);
    ws += w0;
    a.x = fmaf(w0, bf2f(u0.x), a.x); a.y = fmaf(w0, bf2f(u0.y), a.y);
    a.z = fmaf(w0, bf2f(u0.z), a.z); a.w = fmaf(w0, bf2f(u0.w), a.w);
  }
  a.x += b.x; a.y += b.y; a.z += b.z; a.w += b.w; ws += ws2;
  a.x += __shfl_xor(a.x, 16); a.y += __shfl_xor(a.y, 16);
  a.z += __shfl_xor(a.z, 16); a.w += __shfl_xor(a.w, 16);
  ws += __shfl_xor(ws, 16);
  a.x += __shfl_xor(a.x, 32); a.y += __shfl_xor(a.y, 32);
  a.z += __shfl_xor(a.z, 32); a.w += __shfl_xor(a.w, 32);
  ws += __shfl_xor(ws, 32);
  if (g == 0) {
    float4 o = a;
    if (AFFINE) {
      float4 s4 = *(const float4*)(st + q * 4);
      float4 t4 = *(const float4*)(st + 64 + q * 4);
      o.x = fmaf(a.x, s4.x, ws * t4.x);
      o.y = fmaf(a.y, s4.y, ws * t4.y);
      o.z = fmaf(a.z, s4.z, ws * t4.z);
      o.w = fmaf(a.w, s4.w, ws * t4.w);
    }
    ushort4 ub;
    ub.x = f2bf(o.x); ub.y = f2bf(o.y); ub.z = f2bf(o.z); ub.w = f2bf(o.w);
    outb[(size_t)node * 16 + q] = ub;
  }
}

// lap16: packed [N][16] bf16 gather (3.2MB working set -> L2-friendly), pk-based.
// 4 nodes/wave; per node: 4 edge-groups x 4 lanes (q = ushort4 within 32B row).

__global__ __launch_bounds__(256) void lap16_kernel(const ushort4* __restrict__ vb,
                                                    ushort4* __restrict__ outb,
                                                    const int* __restrict__ rowptr,
                                                    const int2* __restrict__ pk, int N) {
  int tid = threadIdx.x, lane = tid & 63, wid = tid >> 6;
  int node = (blockIdx.x * 4 + wid) * 4 + (lane >> 4);
  int sub = lane & 15, g = sub >> 2, q = sub & 3;
  float4 acc = {0.f, 0.f, 0.f, 0.f};
  if (node < N) {
    int r0 = rowptr[node], r1 = rowptr[node + 1];
    int k = r0 + g;
    for (; k + 4 < r1; k += 8) {
      int2 pa = pk[k], pb = pk[k + 4];
      ushort4 ua = vb[(size_t)pa.x * 4 + q];
      ushort4 ub2 = vb[(size_t)pb.x * 4 + q];
      float wa = __int_as_float(pa.y), wb = __int_as_float(pb.y);
      acc.x = fmaf(wa, bf2f(ua.x), acc.x); acc.y = fmaf(wa, bf2f(ua.y), acc.y);
      acc.z = fmaf(wa, bf2f(ua.z), acc.z); acc.w = fmaf(wa, bf2f(ua.w), acc.w);
      acc.x = fmaf(wb, bf2f(ub2.x), acc.x); acc.y = fmaf(wb, bf2f(ub2.y), acc.y);
      acc.z = fmaf(wb, bf2f(ub2.z), acc.z); acc.w = fmaf(wb, bf2f(ub2.w), acc.w);
    }
    if (k < r1) {
      int2 pr = pk[k];
      float w = __int_as_float(pr.y);
      ushort4 u = vb[(size_t)pr.x * 4 + q];
      acc.x = fmaf(w, bf2f(u.x), acc.x); acc.y = fmaf(w, bf2f(u.y), acc.y);
      acc.z = fmaf(w, bf2f(u.z), acc.z); acc.w = fmaf(w, bf2f(u.w), acc.w);
    }
  }
  acc.x += __shfl_xor(acc.x, 4); acc.y += __shfl_xor(acc.y, 4);
  acc.z += __shfl_xor(acc.z, 4); acc.w += __shfl_xor(acc.w, 4);
  acc.x += __shfl_xor(acc.x, 8); acc.y += __shfl_xor(acc.y, 8);
  acc.z += __shfl_xor(acc.z, 8); acc.w += __shfl_xor(acc.w, 8);
  if (node < N && g == 0) {
    ushort4 ub;
    ub.x = f2bf(acc.x); ub.y = f2bf(acc.y); ub.z = f2bf(acc.z); ub.w = f2bf(acc.w);
    outb[(size_t)node * 4 + q] = ub;
  }
}

// ---------------- W' builder (fragment-ordered bf16 + folded bias) ----------------

template <int NMAT, int F_OUT, bool NORMH>
__device__ __forceinline__ void buildW(const float* __restrict__ W, const float* __restrict__ bias,
                                       const float* stPrev,
                                       ushort* __restrict__ fragW, float* __restrict__ biasP,
                                       int f_in_real, int tid, int nth) {
  constexpr int NFRAG = F_OUT / 16;
  constexpr int NKF = NMAT * 2;
  constexpr int TOTF = NKF * NFRAG;
  const int S = f_in_real * F_OUT;
  for (int idx = tid; idx < TOTF * 512; idx += nth) {
    int f = idx >> 9;
    int r = idx & 511;
    int l = r >> 3, j = r & 7;
    int kf = f / NFRAG, nc = f - kf * NFRAG;
    int c = nc * 16 + (l & 15);
    float v = 0.f;
    if (NMAT == 3) {
      int k = (kf & 1) * 32 + (l >> 4) * 8 + j;
      int m = kf >> 1;
      int b = k * F_OUT + c;
      if (m == 0)      { v = W[b] - W[2 * S + b]; if (NORMH) v *= stPrev[k]; }
      else if (m == 1)   v = W[S + b];
      else               v = 2.f * W[2 * S + b];
    } else {
      int kg = kf * 32 + (l >> 4) * 8 + j;   // global k 0..63
      int sub = kg >> 4, kk = kg & 15;
      if (sub < 3 && kk < f_in_real) {
        int b = kk * F_OUT + c;
        if (sub == 0)      v = W[b] - W[2 * S + b];
        else if (sub == 1) v = W[S + b];
        else               v = 2.f * W[2 * S + b];
      }
    }
    fragW[idx] = f2bf(v);
  }
  if (tid < F_OUT) {
    float acc = bias[tid];
    if (NORMH) {
      for (int k = 0; k < 64; ++k)
        acc += stPrev[64 + k] * (W[k * F_OUT + tid] - W[2 * S + k * F_OUT + tid]);
    }
    biasP[tid] = acc;
  }
}

__global__ void __launch_bounds__(1024) wprep1_kernel(const float* __restrict__ W,
                                                      const float* __restrict__ bias,
                                                      ushort* __restrict__ fragW,
                                                      float* __restrict__ biasP, int finr) {
  buildW<1, 64, false>(W, bias, nullptr, fragW, biasP, finr, threadIdx.x, 1024);
}

// ---------------- MFMA mm ----------------
// NMAT=3: A0/A1/A2 = [N][64] bf16 buffers. NMAT=1: A0/A1/A2 = packed [N][16]
// buffers (h16p,t1p,t2p); k>=48 reads a 64B zero stub (Az).
// mfma_f32_16x16x32_bf16: A: lane l -> A[l&15][(l>>4)*8+j];
// B: lane l -> B[(l>>4)*8+j][l&15]; D: lane l, reg r -> C[(l>>4)*4+r][l&15].

template <int NMAT, int F_OUT>
__global__ __launch_bounds__(256) void mmfma_kernel(
    const ushort* __restrict__ A0, const ushort* __restrict__ A1, const ushort* __restrict__ A2,
    const ushort* __restrict__ Az,
    ushort* __restrict__ outb,
    const ushort* __restrict__ fragW, const float* __restrict__ biasP,
    const float* __restrict__ aP,
    float* __restrict__ bp, int N, int ntiles) {
  constexpr int NFRAG = F_OUT / 16;
  constexpr int NKF = NMAT * 2;
  constexpr int TOTF = NKF * NFRAG;
  __shared__ float red[4 * 2 * 64];          // [wave][stat][col]
  int tid = threadIdx.x;
  for (int idx = tid; idx < 512; idx += 256) red[idx] = 0.f;
  __syncthreads();

  const int lane = tid & 63, wid = tid >> 6;
  const int rg = lane >> 4, cl = lane & 15;
  const float alpha = aP[0];

  short8 bfr[TOTF];
#pragma unroll
  for (int f = 0; f < TOTF; ++f)
    bfr[f] = *(const short8*)&fragW[f * 512 + lane * 8];
  float bi[NFRAG];
#pragma unroll
  for (int nc = 0; nc < NFRAG; ++nc) bi[nc] = biasP[nc * 16 + cl];

  float ssum[NFRAG], ssq[NFRAG];
#pragma unroll
  for (int nc = 0; nc < NFRAG; ++nc) { ssum[nc] = 0.f; ssq[nc] = 0.f; }

  for (int tile = blockIdx.x; tile < ntiles; tile += gridDim.x) {
    const int nb = tile * 64 + wid * 16;
    floatx4 acc[NFRAG];
#pragma unroll
    for (int nc = 0; nc < NFRAG; ++nc) acc[nc] = (floatx4){0.f, 0.f, 0.f, 0.f};

#pragma unroll
    for (int kf = 0; kf < NKF; ++kf) {
      short8 a;
      if (NMAT == 3) {
        const ushort* Ap = (kf < 2 ? A0 : (kf < 4 ? A1 : A2));
        a = *(const short8*)(Ap + (size_t)(nb + cl) * 64 + (kf & 1) * 32 + rg * 8);
      } else {
        int k0 = kf * 32 + rg * 8;           // 0..56
        int sb = k0 >> 4;                    // 0..3 (per-lane)
        const ushort* Ap = sb == 0 ? A0 : (sb == 1 ? A1 : (sb == 2 ? A2 : Az));
        size_t off = (sb == 3) ? 0 : ((size_t)(nb + cl) * 16 + (k0 & 15));
        a = *(const short8*)(Ap + off);
      }
#pragma unroll
      for (int nc = 0; nc < NFRAG; ++nc)
        acc[nc] = __builtin_amdgcn_mfma_f32_16x16x32_bf16(a, bfr[kf * NFRAG + nc], acc[nc], 0, 0, 0);
    }

#pragma unroll
    for (int nc = 0; nc < NFRAG; ++nc) {
      int c = nc * 16 + cl;
#pragma unroll
      for (int r = 0; r < 4; ++r) {
        int node = nb + rg * 4 + r;
        if (node < N) {
          float t = acc[nc][r] + bi[nc];
          t = t > 0.f ? t : alpha * t;
          ssum[nc] += t; ssq[nc] += t * t;
          outb[(size_t)node * 64 + c] = f2bf(t);
        }
      }
    }
  }

#pragma unroll
  for (int nc = 0; nc < NFRAG; ++nc) {
    ssum[nc] += __shfl_xor(ssum[nc], 16); ssum[nc] += __shfl_xor(ssum[nc], 32);
    ssq[nc]  += __shfl_xor(ssq[nc], 16);  ssq[nc]  += __shfl_xor(ssq[nc], 32);
  }
  if (lane < 16) {
#pragma unroll
    for (int nc = 0; nc < NFRAG; ++nc) {
      red[(wid * 2 + 0) * 64 + nc * 16 + lane] = ssum[nc];
      red[(wid * 2 + 1) * 64 + nc * 16 + lane] = ssq[nc];
    }
  }
  __syncthreads();
  if (tid < 128) {
    int col = tid & 63, stat = tid >> 6;
    float tot = red[(0 * 2 + stat) * 64 + col] + red[(1 * 2 + stat) * 64 + col]
              + red[(2 * 2 + stat) * 64 + col] + red[(3 * 2 + stat) * 64 + col];
    bp[(size_t)blockIdx.x * 128 + stat * 64 + col] = tot;
  }
}

// ---------------- BN stats reduce -> affine (s,t); optionally builds next layer's W' ----------------

template <int NMAT_N, int F_OUT_N, bool BUILD>
__global__ void stats_kernel(const float* __restrict__ bp, int nb,
                             const float* __restrict__ g, const float* __restrict__ be,
                             float* __restrict__ st, int F_OUT, float invN,
                             const float* __restrict__ Wn, const float* __restrict__ bn,
                             ushort* __restrict__ fragWn, float* __restrict__ biasPn, int finrN) {
  __shared__ float red[1024];
  __shared__ float stSh[128];
  int tid = threadIdx.x;
  int t = tid & 127, c = tid >> 7;
  float s = 0.f;
  for (int w = c; w < nb; w += 8) s += bp[(size_t)w * 128 + t];
  red[tid] = s;
  __syncthreads();
  if (tid < 128) {
    float tot = 0.f;
    for (int cc = 0; cc < 8; ++cc) tot += red[cc * 128 + tid];
    red[tid] = tot;
  }
  __syncthreads();
  if (tid < F_OUT) {
    float sum = red[tid], sq = red[64 + tid];
    float mu = sum * invN;
    float var = sq * invN - mu * mu;
    float sc = g[tid] * rsqrtf(var + BN_EPS);
    st[tid] = sc;        stSh[tid] = sc;
    st[64 + tid] = be[tid] - mu * sc;
    stSh[64 + tid] = be[tid] - mu * sc;
  }
  if (BUILD) {
    __syncthreads();
    buildW<NMAT_N, F_OUT_N, true>(Wn, bn, stSh, fragWn, biasPn, finrN, tid, 1024);
  }
}

// ---------------- final MLP: register-tiled GEMM chain ----------------

__global__ __launch_bounds__(256) void mlp_kernel(const ushort* __restrict__ hb,
    const float* __restrict__ st,
    const float* __restrict__ w1, const float* __restrict__ b1,
    const float* __restrict__ w2, const float* __restrict__ b2,
    const float* __restrict__ w3, const float* __restrict__ b3,
    float* __restrict__ out, int N, int ntiles) {
  __shared__ float Wl[3][1024];
  __shared__ float Bl[3][32];
  __shared__ float S4[32], T4[32];
  __shared__ float act[2][128][36];
  int tid = threadIdx.x;
  for (int idx = tid; idx < 1024; idx += 256) {
    Wl[0][idx] = w1[idx];
    Wl[1][idx] = w2[idx];
    Wl[2][idx] = w3[idx];
  }
  if (tid < 32) {
    Bl[0][tid] = b1[tid]; Bl[1][tid] = b2[tid]; Bl[2][tid] = b3[tid];
    S4[tid] = st[tid]; T4[tid] = st[64 + tid];
  }
  __syncthreads();

  const int cg = tid & 7, ng = tid >> 3;
  const int c0 = cg * 4;
  const int nl = ng * 4;

  for (int tile = blockIdx.x; tile < ntiles; tile += gridDim.x) {
    const int node0 = tile * 128 + nl;
    float acc[4][4];

#pragma unroll
    for (int j = 0; j < 4; ++j)
#pragma unroll
      for (int c = 0; c < 4; ++c) acc[j][c] = 0.f;
#pragma unroll
    for (int kb = 0; kb < 8; ++kb) {
      float ar[4][4];
#pragma unroll
      for (int j = 0; j < 4; ++j) {
        int node = node0 + j;
        if (node < N) {
          ushort4 u = *(const ushort4*)(hb + (size_t)node * 64 + kb * 4);
          ar[j][0] = fmaf(bf2f(u.x), S4[kb * 4 + 0], T4[kb * 4 + 0]);
          ar[j][1] = fmaf(bf2f(u.y), S4[kb * 4 + 1], T4[kb * 4 + 1]);
          ar[j][2] = fmaf(bf2f(u.z), S4[kb * 4 + 2], T4[kb * 4 + 2]);
          ar[j][3] = fmaf(bf2f(u.w), S4[kb * 4 + 3], T4[kb * 4 + 3]);
        } else {
          ar[j][0] = ar[j][1] = ar[j][2] = ar[j][3] = 0.f;
        }
      }
#pragma unroll
      for (int kk = 0; kk < 4; ++kk) {
        float br[4];
        *(float4*)br = *(const float4*)(&Wl[0][(kb * 4 + kk) * 32 + c0]);
#pragma unroll
        for (int j = 0; j < 4; ++j)
#pragma unroll
          for (int c = 0; c < 4; ++c)
            acc[j][c] = fmaf(ar[j][kk], br[c], acc[j][c]);
      }
    }
#pragma unroll
    for (int j = 0; j < 4; ++j) {
      float v[4];
#pragma unroll
      for (int c = 0; c < 4; ++c) v[c] = fmaxf(acc[j][c] + Bl[0][c0 + c], 0.f);
      *(float4*)(&act[0][nl + j][c0]) = *(float4*)v;
    }
    __syncthreads();

#pragma unroll
    for (int j = 0; j < 4; ++j)
#pragma unroll
      for (int c = 0; c < 4; ++c) acc[j][c] = 0.f;
#pragma unroll
    for (int kb = 0; kb < 8; ++kb) {
      float ar[4][4];
#pragma unroll
      for (int j = 0; j < 4; ++j)
        *(float4*)ar[j] = *(const float4*)(&act[0][nl + j][kb * 4]);
#pragma unroll
      for (int kk = 0; kk < 4; ++kk) {
        float br[4];
        *(float4*)br = *(const float4*)(&Wl[1][(kb * 4 + kk) * 32 + c0]);
#pragma unroll
        for (int j = 0; j < 4; ++j)
#pragma unroll
          for (int c = 0; c < 4; ++c)
            acc[j][c] = fmaf(ar[j][kk], br[c], acc[j][c]);
      }
    }
#pragma unroll
    for (int j = 0; j < 4; ++j) {
      float v[4];
#pragma unroll
      for (int c = 0; c < 4; ++c) v[c] = fmaxf(acc[j][c] + Bl[1][c0 + c], 0.f);
      *(float4*)(&act[1][nl + j][c0]) = *(float4*)v;
    }
    __syncthreads();

#pragma unroll
    for (int j = 0; j < 4; ++j)
#pragma unroll
      for (int c = 0; c < 4; ++c) acc[j][c] = 0.f;
#pragma unroll
    for (int kb = 0; kb < 8; ++kb) {
      float ar[4][4];
#pragma unroll
      for (int j = 0; j < 4; ++j)
        *(float4*)ar[j] = *(const float4*)(&act[1][nl + j][kb * 4]);
#pragma unroll
      for (int kk = 0; kk < 4; ++kk) {
        float br[4];
        *(float4*)br = *(const float4*)(&Wl[2][(kb * 4 + kk) * 32 + c0]);
#pragma unroll
        for (int j = 0; j < 4; ++j)
#pragma unroll
          for (int c = 0; c < 4; ++c)
            acc[j][c] = fmaf(ar[j][kk], br[c], acc[j][c]);
      }
    }
#pragma unroll
    for (int j = 0; j < 4; ++j) {
      int node = node0 + j;
      if (node < N) {
        float v[4];
#pragma unroll
        for (int c = 0; c < 4; ++c) v[c] = acc[j][c] + Bl[2][c0 + c];
        *(float4*)(out + (size_t)node * 32 + c0) = *(float4*)v;
      }
    }
    __syncthreads();
  }
}

// ---------------- host ----------------

extern "C" void kernel_launch(void* const* d_in, const int* in_sizes, int n_in,
                              void* d_out, int out_size, void* d_ws, size_t ws_size,
                              hipStream_t stream) {
  const float* x   = (const float*)d_in[0];
  const float* pos = (const float*)d_in[1];
  const float* nrm = (const float*)d_in[2];
  const int*   ei  = (const int*)d_in[3];
  const float* W1p = (const float*)d_in[4];
  const float* b1p = (const float*)d_in[5];
  const float* a1p = (const float*)d_in[6];
  const float* g1p = (const float*)d_in[7];
  const float* be1p= (const float*)d_in[8];
  const float* W2p = (const float*)d_in[9];
  const float* b2p = (const float*)d_in[10];
  const float* a2p = (const float*)d_in[11];
  const float* g2p = (const float*)d_in[12];
  const float* be2p= (const float*)d_in[13];
  const float* W3p = (const float*)d_in[14];
  const float* b3p = (const float*)d_in[15];
  const float* a3p = (const float*)d_in[16];
  const float* g3p = (const float*)d_in[17];
  const float* be3p= (const float*)d_in[18];
  const float* W4p = (const float*)d_in[19];
  const float* b4p = (const float*)d_in[20];
  const float* a4p = (const float*)d_in[21];
  const float* g4p = (const float*)d_in[22];
  const float* be4p= (const float*)d_in[23];
  const float* h1w = (const float*)d_in[24];
  const float* h1b = (const float*)d_in[25];
  const float* h2w = (const float*)d_in[26];
  const float* h2b = (const float*)d_in[27];
  const float* h3w = (const float*)d_in[28];
  const float* h3b = (const float*)d_in[29];

  const int N = in_sizes[0] / 3;
  const int E = in_sizes[3] / 2;
  const int* src = ei;
  const int* dst = ei + E;

  const int NW = (N + 3) / 4;
  const size_t ldsBytes = (size_t)NW * 4;
  const int slice = (E + HB - 1) / HB;

  char* p = (char*)d_ws;
  auto alloc = [&](size_t bytes) -> void* {
    void* r = (void*)p;
    p += (bytes + 255) & ~(size_t)255;
    return r;
  };
  float*    dis      = (float*)   alloc((size_t)N * 4);
  int*      rowptr   = (int*)     alloc((size_t)(N + 1) * 4);
  int*      cnt      = (int*)     alloc((size_t)N * 4);
  int*      bsums    = (int*)     alloc(4096 * 4);
  unsigned* partialsA= (unsigned*)alloc((size_t)HB * NW * 4);   // -> baseTbl
  unsigned* partialsB= (unsigned*)alloc((size_t)HB * NW * 4);   // -> pk (E*8 fits)
  int2*     pk       = (int2*)partialsB;
  ushort*   bufHb    = (ushort*)  alloc((size_t)N * 64 * 2);
  ushort*   bufT1b   = (ushort*)  alloc((size_t)N * 64 * 2);
  ushort*   bufT2b   = (ushort*)  alloc((size_t)N * 64 * 2);
  ushort*   h16p     = (ushort*)  alloc((size_t)N * 16 * 2);    // packed layer-1
  ushort*   t1p      = (ushort*)  alloc((size_t)N * 16 * 2);
  ushort*   t2p      = (ushort*)  alloc((size_t)N * 16 * 2);
  ushort*   zerob    = (ushort*)  alloc(64);
  const int MMB = 782;
  float*    bp       = (float*)   alloc((size_t)MMB * 128 * 4);
  float*    stats    = (float*)   alloc(512 * 4);
  ushort*   fragW    = (ushort*)  alloc(24 * 512 * 2);          // max TOTF=24
  float*    biasP    = (float*)   alloc(64 * 4);
  float* st1 = stats, *st2 = stats + 128, *st3 = stats + 256, *st4 = stats + 384;

  int gN = (N + 255) / 256;
  hipMemsetAsync(zerob, 0, 64, stream);
  hist_lds_kernel<<<HB, 1024, ldsBytes, stream>>>(src, E, slice, partialsA, NW);
  hist_lds_kernel<<<HB, 1024, ldsBytes, stream>>>(dst, E, slice, partialsB, NW);
  combine_kernel<<<(NW + 255) / 256, 256, 0, stream>>>(partialsA, partialsB, dis, cnt, NW, N);
  scan1_kernel<<<gN, 256, 0, stream>>>(cnt, N, rowptr, bsums);
  scan2_kernel<<<1, 1024, 0, stream>>>(bsums, gN, rowptr, N);
  scan3_kernel<<<gN, 256, 0, stream>>>(rowptr, bsums, N);
  scatter2_kernel<<<HB, 1024, ldsBytes, stream>>>(src, dst, E, slice, partialsA, NW, rowptr, dis, pk);
  pack_kernel<<<(N * 16 + 255) / 256, 256, 0, stream>>>(x, pos, nrm, h16p, N);
  wprep1_kernel<<<1, 1024, 0, stream>>>(W1p, b1p, fragW, biasP, 9);

  const float invN = 1.f / (float)N;
  int g64 = (N + 3) / 4, g16 = (N + 15) / 16;
  const int ntiles = (N + 63) / 64;
  const int ntilesM = (N + 127) / 128;

  // layer 1: packed h16p -> t1p -> t2p; mmfma reads 3 packed buffers + zero
  lap16_kernel<<<g16, 256, 0, stream>>>((const ushort4*)h16p, (ushort4*)t1p, rowptr, pk, N);
  lap16_kernel<<<g16, 256, 0, stream>>>((const ushort4*)t1p, (ushort4*)t2p, rowptr, pk, N);
  mmfma_kernel<1, 64><<<MMB, 256, 0, stream>>>(h16p, t1p, t2p, zerob, bufHb,
      fragW, biasP, a1p, bp, N, ntiles);
  stats_kernel<3, 64, true><<<1, 1024, 0, stream>>>(bp, MMB, g1p, be1p, st1, 64, invN,
      W2p, b2p, fragW, biasP, 64);

  // layer 2 (in-place on bufHb)
  lap64_kernel<true><<<g64, 256, 0, stream>>>((const ushort4*)bufHb, (ushort4*)bufT1b,
      rowptr, pk, st1, N);
  lap64_kernel<false><<<g64, 256, 0, stream>>>((const ushort4*)bufT1b, (ushort4*)bufT2b,
      rowptr, pk, nullptr, N);
  mmfma_kernel<3, 64><<<MMB, 256, 0, stream>>>(bufHb, bufT1b, bufT2b, nullptr, bufHb,
      fragW, biasP, a2p, bp, N, ntiles);
  stats_kernel<3, 64, true><<<1, 1024, 0, stream>>>(bp, MMB, g2p, be2p, st2, 64, invN,
      W3p, b3p, fragW, biasP, 64);

  // layer 3
  lap64_kernel<true><<<g64, 256, 0, stream>>>((const ushort4*)bufHb, (ushort4*)bufT1b,
      rowptr, pk, st2, N);
  lap64_kernel<false><<<g64, 256, 0, stream>>>((const ushort4*)bufT1b, (ushort4*)bufT2b,
      rowptr, pk, nullptr, N);
  mmfma_kernel<3, 64><<<MMB, 256, 0, stream>>>(bufHb, bufT1b, bufT2b, nullptr, bufHb,
      fragW, biasP, a3p, bp, N, ntiles);
  stats_kernel<3, 32, true><<<1, 1024, 0, stream>>>(bp, MMB, g3p, be3p, st3, 64, invN,
      W4p, b4p, fragW, biasP, 64);

  // layer 4: 64 -> 32 (rows stride 64, cols 0-31 rewritten)
  lap64_kernel<true><<<g64, 256, 0, stream>>>((const ushort4*)bufHb, (ushort4*)bufT1b,
      rowptr, pk, st3, N);
  lap64_kernel<false><<<g64, 256, 0, stream>>>((const ushort4*)bufT1b, (ushort4*)bufT2b,
      rowptr, pk, nullptr, N);
  mmfma_kernel<3, 32><<<MMB, 256, 0, stream>>>(bufHb, bufT1b, bufT2b, nullptr, bufHb,
      fragW, biasP, a4p, bp, N, ntiles);
  stats_kernel<3, 64, false><<<1, 1024, 0, stream>>>(bp, MMB, g4p, be4p, st4, 32, invN,
      nullptr, nullptr, nullptr, nullptr, 0);

  // final MLP (applies st4 affine on load)
  mlp_kernel<<<ntilesM, 256, 0, stream>>>(bufHb, st4, h1w, h1b, h2w, h2b, h3w, h3b,
      (float*)d_out, N, ntilesM);
}